// Round 15
// baseline (423.845 us; speedup 1.0000x reference)
//
#include <hip/hip_runtime.h>

#define NN 50000
#define NE 800000
#define DBINS 1024

typedef __attribute__((ext_vector_type(8))) short bf16x8;
typedef __attribute__((ext_vector_type(4))) float f32x4;
typedef __attribute__((ext_vector_type(2))) float f32x2;

__device__ __forceinline__ unsigned short f2bf(float f) {
    union { float f; unsigned u; } v; v.f = f;
    unsigned r = v.u + 0x7FFFu + ((v.u >> 16) & 1u);
    return (unsigned short)(r >> 16);
}

// 32-bit-offset gathers (uniform 64-bit base + 32-bit voffset)
__device__ __forceinline__ int4 ld_ep2(const int4* ep, unsigned idx, int which) {
    return *(const int4*)((const char*)ep + (size_t)(idx * 32u + (unsigned)which * 16u));
}
__device__ __forceinline__ unsigned ld_xu(const unsigned* X, unsigned byteoff) {
    return *(const unsigned*)((const char*)X + (size_t)byteoff);
}

// dword of 2 packed bf16 (lo, hi) -> f32x2 {lo, hi}
__device__ __forceinline__ f32x2 unpack2(unsigned u) {
    union { unsigned u; float f; } a, b;
    a.u = u << 16;
    b.u = u & 0xFFFF0000u;
    return f32x2{a.f, b.f};
}

// ---- forced VOP3P packed-f32 with op_sel broadcasts (validated r3/r4) ----
__device__ __forceinline__ f32x2 pk_mul_hib(f32x2 w, f32x2 x) {
    f32x2 d;
    asm("v_pk_mul_f32 %0, %1, %2 op_sel:[1,0] op_sel_hi:[1,1]"
        : "=v"(d) : "v"(w), "v"(x));
    return d;
}
__device__ __forceinline__ void pk_fma_lob(f32x2& h, f32x2 w, f32x2 t) {
    asm("v_pk_fma_f32 %0, %1, %2, %0 op_sel:[0,0,0] op_sel_hi:[0,1,1]"
        : "+v"(h) : "v"(w), "v"(t));
}

// bf16 LDS A-fragment layout (16 nodes):
//   element (kstep kk, r = k&31, node m) at ushort index
//   kk*544 + (r>>3)*136 + m*8 + (r&7)
__device__ __forceinline__ int us_idx(int kk, int r, int m) {
    return kk*544 + (r >> 3)*136 + m*8 + (r & 7);
}

// packed hat-weight accumulate; weights preloaded per edge (bf16 pairs).
// Branch-free dense form: 25 pk_fma — register-resident (sparse-switch and
// MFMA-keeper variants both spilled; this is the verified floor).
template<bool HS>
__device__ __forceinline__ void edge_acc2(f32x2* h, f32x2& hs,
                                          const int4& pa, const int4& pb, f32x2 x) {
    f32x2 wxy[5];
    wxy[0] = unpack2((unsigned)pa.y);
    wxy[1] = unpack2((unsigned)pa.z);
    wxy[2] = unpack2((unsigned)pa.w);
    wxy[3] = unpack2((unsigned)pb.x);
    wxy[4] = unpack2((unsigned)pb.y);
    if (HS) hs += x;
#pragma unroll
    for (int r1 = 0; r1 < 5; ++r1) {
        f32x2 ty = pk_mul_hib(wxy[r1], x);
#pragma unroll
        for (int r0 = 0; r0 < 5; ++r0)
            pk_fma_lob(h[r1*5 + r0], wxy[r0], ty);
    }
}

__device__ __forceinline__ float eh_reduce(f32x2 v, int eh, int stride) {
    float mine  = eh ? v.y : v.x;
    float other = eh ? v.x : v.y;
    return mine + __shfl_xor(other, stride);
}

// ---------------- setup kernels ----------------
__global__ __launch_bounds__(256) void k_zero(int* degi, int* cur, float* stats,
                                              int* dcnt, int* dcur,
                                              unsigned* xz, unsigned* hz) {
    int i = blockIdx.x*256 + threadIdx.x;
    int stride = gridDim.x*256;
    for (int j = i; j < NN; j += stride) { degi[j] = 0; cur[j] = 0; }
    if (i < 384) stats[i] = 0.f;
    if (i < DBINS) { dcnt[i] = 0; dcur[i] = 0; }
    if (i < 16) xz[i] = 0u;
    if (i < 32) hz[i] = 0u;
}

__global__ __launch_bounds__(256) void k_hist(const int* __restrict__ dst, int* degi) {
    int e = blockIdx.x*256 + threadIdx.x;
    if (e < NE) atomicAdd(&degi[dst[e]], 1);
}

// fused: blocks 0..48 = scan of CEIL4(deg) -> padded offsets;
//        blocks 49..244 = 1024-bin LDS-staged degree histogram.
__global__ __launch_bounds__(256) void k_sbdh(const int* __restrict__ degi,
                                              int* off, int* bsum, int* dcnt) {
    __shared__ int lh[DBINS];
    int t = threadIdx.x;
    if (blockIdx.x < 49) {
        int base = blockIdx.x * 1024;
        int v[4]; int s = 0;
#pragma unroll
        for (int j = 0; j < 4; j++) {
            int idx = base + t*4 + j;
            v[j] = (idx < NN) ? ((degi[idx] + 3) & ~3) : 0;
            s += v[j];
        }
        lh[t] = s; __syncthreads();
        for (int ofs = 1; ofs < 256; ofs <<= 1) {
            int x = (t >= ofs) ? lh[t - ofs] : 0;
            __syncthreads();
            lh[t] += x;
            __syncthreads();
        }
        int ex = lh[t] - s;
#pragma unroll
        for (int j = 0; j < 4; j++) {
            int idx = base + t*4 + j;
            if (idx < NN) off[idx] = ex;
            ex += v[j];
        }
        if (t == 255) bsum[blockIdx.x] = lh[255];
    } else {
#pragma unroll
        for (int j = 0; j < DBINS/256; ++j) lh[t + 256*j] = 0;
        __syncthreads();
        int n = (blockIdx.x - 49)*256 + t;
        if (n < NN) atomicAdd(&lh[min(degi[n], DBINS-1)], 1);
        __syncthreads();
#pragma unroll
        for (int j = 0; j < DBINS/256; ++j) {
            int b = t + 256*j;
            if (lh[b]) atomicAdd(&dcnt[b], lh[b]);
        }
    }
}

// fused: block 0 = top-level scan of bsum; block 1 = 1024-bin degree scan
__global__ __launch_bounds__(256) void k_topscan(const int* __restrict__ bsum,
                                                 int* bpre, int nb,
                                                 const int* __restrict__ dcnt,
                                                 int* dbase) {
    __shared__ int sh[256];
    int t = threadIdx.x;
    if (blockIdx.x == 0) {
        int s = (t < nb) ? bsum[t] : 0;
        sh[t] = s; __syncthreads();
        for (int ofs = 1; ofs < 256; ofs <<= 1) {
            int x = (t >= ofs) ? sh[t - ofs] : 0;
            __syncthreads();
            sh[t] += x;
            __syncthreads();
        }
        if (t < nb) bpre[t] = sh[t] - s;
    } else {
        int v[4]; int s = 0;
#pragma unroll
        for (int j = 0; j < 4; j++) { v[j] = dcnt[t*4 + j]; s += v[j]; }
        sh[t] = s; __syncthreads();
        for (int ofs = 1; ofs < 256; ofs <<= 1) {
            int x = (t >= ofs) ? sh[t - ofs] : 0;
            __syncthreads();
            sh[t] += x;
            __syncthreads();
        }
        int ex = sh[t] - s;
#pragma unroll
        for (int j = 0; j < 4; j++) { dbase[t*4 + j] = ex; ex += v[j]; }
    }
}

__global__ __launch_bounds__(256) void k_scan_add(int* off, const int* __restrict__ bpre,
                                                  const int* __restrict__ degi) {
    int i = blockIdx.x*256 + threadIdx.x;
    if (i < NN) {
        int v = off[i] + bpre[i >> 10];
        off[i] = v;
        if (i == NN - 1) off[NN] = v + ((degi[i] + 3) & ~3);
    }
}

// fused: counting-sort scatter (LDS-staged) + pad fill
__global__ __launch_bounds__(256) void k_pscatter_pad(const int* __restrict__ degi,
                                                      const int* __restrict__ dbase,
                                                      int* dcur, int* perm,
                                                      const int* __restrict__ off,
                                                      int4* __restrict__ ep) {
    __shared__ int lh[DBINS];
    __shared__ int lb[DBINS];
    int t = threadIdx.x;
#pragma unroll
    for (int j = 0; j < DBINS/256; ++j) lh[t + 256*j] = 0;
    __syncthreads();
    int n = blockIdx.x*256 + t;
    int d = 0, lr = 0;
    bool act = (n < NN);
    if (act) {
        d = min(degi[n], DBINS-1);
        lr = atomicAdd(&lh[d], 1);
    }
    __syncthreads();
#pragma unroll
    for (int j = 0; j < DBINS/256; ++j) {
        int b = t + 256*j;
        int c = lh[b];
        lb[b] = c ? atomicAdd(&dcur[b], c) : 0;
    }
    __syncthreads();
    if (act) {
        perm[dbase[d] + lb[d] + lr] = n;
        int base = off[n] + degi[n];
        int end  = off[n + 1];
        for (int p = base; p < end; ++p) {
            ep[2*p]     = make_int4(NN, 0, 0, 0);
            ep[2*p + 1] = make_int4(0, 0, 0, 0);
        }
    }
}

__device__ __forceinline__ void wprep_body(int tid, const float* W, const float* root,
                                           int KTC, unsigned short* Wb) {
    int lane = tid & 63, cot = (tid >> 6) & 3, kk = tid >> 8;
    int co = 16*cot + (lane & 15);
    int kbase = kk*32 + ((lane >> 4) * 8);
    union { unsigned short s[8]; uint4 v; } u;
#pragma unroll
    for (int j = 0; j < 8; j++) {
        int k = kbase + j;
        float val = (k < KTC) ? W[(size_t)k*64 + co] : root[(size_t)(k - KTC)*64 + co];
        u.s[j] = f2bf(val);
    }
    *(uint4*)(Wb + (size_t)tid * 8) = u.v;
}

// fused: blocks 0..3124 edge scatter (dense weight records);
//        blocks 3125..4687 x->bf16; 4688..4713 Wb1; 4714..4715 WbS; rest Wb2.
__global__ __launch_bounds__(256) void k_scatter_prep(
        const int* __restrict__ src, const int* __restrict__ dst,
        const float* __restrict__ ea, const int* __restrict__ off, int* cur,
        int4* __restrict__ ep,
        const float* __restrict__ x, unsigned short* __restrict__ xb,
        const float* __restrict__ w1, const float* __restrict__ r1,
        unsigned short* Wb1,
        const float* __restrict__ wsN, const float* __restrict__ rs,
        unsigned short* WbS,
        const float* __restrict__ w2, const float* __restrict__ r2,
        unsigned short* Wb2) {
    int b = blockIdx.x, t = threadIdx.x;
    if (b < 3125) {
        int e = b*256 + t;
        if (e >= NE) return;
        int d = dst[e];
        int p = off[d] + atomicAdd(&cur[d], 1);
        float v0 = ea[2*e]     * 4.f;
        float v1 = ea[2*e + 1] * 4.f;
        unsigned w[5];
#pragma unroll
        for (int r = 0; r < 5; ++r) {
            float wx = fmaxf(1.f - fabsf(v0 - (float)r), 0.f);
            float wy = fmaxf(1.f - fabsf(v1 - (float)r), 0.f);
            w[r] = (unsigned)f2bf(wx) | ((unsigned)f2bf(wy) << 16);
        }
        ep[2*p]     = make_int4(src[e], (int)w[0], (int)w[1], (int)w[2]);
        ep[2*p + 1] = make_int4((int)w[3], (int)w[4], 0, 0);
    } else if (b < 3125 + 1563) {
        int i = (b - 3125)*256 + t;
        if (i >= NN*8) return;
        float4 v = ((const float4*)x)[i];
        uint2 pk;
        pk.x = (unsigned)f2bf(v.x) | ((unsigned)f2bf(v.y) << 16);
        pk.y = (unsigned)f2bf(v.z) | ((unsigned)f2bf(v.w) << 16);
        ((uint2*)xb)[i] = pk;
    } else if (b < 3125 + 1589) {
        wprep_body((b - 3125 - 1563)*256 + t, w1, r1, 800, Wb1);
    } else if (b < 3125 + 1591) {
        wprep_body((b - 3125 - 1589)*256 + t, wsN, rs, 32, WbS);
    } else {
        wprep_body((b - 3125 - 1591)*256 + t, w2, r2, 1600, Wb2);
    }
}

// ---------------- conv1 + convS fused: 16 nodes/block ----------------
// LPT order: heaviest (highest-degree) blocks first (perm is degree-ascending).
__global__ __launch_bounds__(512, 4) void k_conv1s(
        const unsigned* __restrict__ Xbf,        // [NN+1][16] dwords (32 bf16 ch)
        const int* __restrict__ off,
        const int* __restrict__ degi,
        const int4* __restrict__ ep,
        const int* __restrict__ perm,
        const unsigned short* __restrict__ Wb1,
        const unsigned short* __restrict__ WbS,
        const float* __restrict__ b1,
        const float* __restrict__ bs,
        float* __restrict__ agg1,
        float* __restrict__ aggS) {
    __shared__ __align__(16) unsigned short hb[28*544];  // 30.5 KB
    const int t = threadIdx.x;
    const int g = t >> 5;
    const int q = t & 31;
    const int chp = q & 15;
    const int eh = q >> 4;
    const int n0 = NN - 16 - blockIdx.x * 16;   // LPT order
    const int n = perm[n0 + g];

    f32x2 h[25], hs = {0.f, 0.f};
#pragma unroll
    for (int i = 0; i < 25; ++i) h[i] = f32x2{0.f, 0.f};

    const int ebeg = off[n], eend = off[n + 1];
    const float rdeg = 1.f / (float)max(degi[n], 1);

    for (int i = ebeg; i < eend; i += 4) {
        const unsigned i0 = (unsigned)(i + eh), i1 = (unsigned)(i + 2 + eh);
        int4 a0 = ld_ep2(ep, i0, 0), b0 = ld_ep2(ep, i0, 1);
        int4 a1 = ld_ep2(ep, i1, 0), b1 = ld_ep2(ep, i1, 1);
        unsigned u0 = ld_xu(Xbf, (unsigned)a0.x * 64u + (unsigned)chp * 4u);
        unsigned u1 = ld_xu(Xbf, (unsigned)a1.x * 64u + (unsigned)chp * 4u);
        edge_acc2<true>(h, hs, a0, b0, unpack2(u0));
        edge_acc2<true>(h, hs, a1, b1, unpack2(u1));
    }

    const int c = 2*chp + eh;
    const int bw = us_idx(0, c, g);
#pragma unroll
    for (int wi = 0; wi < 25; ++wi)
        hb[wi*544 + bw] = f2bf(eh_reduce(h[wi], eh, 16) * rdeg);
    hb[26*544 + bw] = f2bf(eh_reduce(hs, eh, 16) * rdeg);
    {
        unsigned ux = Xbf[(unsigned)n * 16u + (unsigned)chp];
        unsigned short xb = eh ? (unsigned short)(ux >> 16)
                               : (unsigned short)(ux & 0xFFFFu);
        hb[25*544 + bw] = xb;
        hb[27*544 + bw] = xb;
    }
    __syncthreads();

    const int lane = t & 63, w = t >> 6;
    const int m = lane & 15, qq = lane >> 4;
    const int co = (w & 3)*16 + m;
    const int4 pn = ((const int4*)perm)[(n0 >> 2) + qq];
    const int prow[4] = {pn.x, pn.y, pn.z, pn.w};
    if (w < 4) {
        f32x4 acc = {0.f, 0.f, 0.f, 0.f};
        for (int kk = 0; kk < 26; ++kk) {
            bf16x8 av = *(const bf16x8*)&hb[kk*544 + qq*136 + m*8];
            bf16x8 bv = *(const bf16x8*)(Wb1 + (size_t)((kk*4 + w)*64 + lane) * 8);
            acc = __builtin_amdgcn_mfma_f32_16x16x32_bf16(av, bv, acc, 0, 0, 0);
        }
        const float bb = b1[co];
#pragma unroll
        for (int r = 0; r < 4; ++r)
            agg1[(size_t)prow[r]*64 + co] = acc[r] + bb;
    } else {
        f32x4 accs = {0.f, 0.f, 0.f, 0.f};
#pragma unroll
        for (int s = 0; s < 2; ++s) {
            bf16x8 av = *(const bf16x8*)&hb[(26 + s)*544 + qq*136 + m*8];
            bf16x8 bv = *(const bf16x8*)(WbS + (size_t)((s*4 + (w & 3))*64 + lane) * 8);
            accs = __builtin_amdgcn_mfma_f32_16x16x32_bf16(av, bv, accs, 0, 0, 0);
        }
        const float bb = bs[co];
#pragma unroll
        for (int r = 0; r < 4; ++r)
            aggS[(size_t)prow[r]*64 + co] = accs[r] + bb;
    }
}

// ---------------- conv2: 16 nodes/block, K-split phase B ----------------
// 512 threads, 8 waves. Half-wave (t>>5) owns one node; lane chp = channel
// pair (c0=2chp, c1=2chp+1) -> no eh_reduce, dword dumps (conflict-free).
// LDS holds 26 of 52 K-steps (27.6 KB): dump wi 0..12 -> MFMA -> barrier ->
// dump wi 13..24 + x -> MFMA. LPT block order.
// Edge loop: 4-edge static batch (4 independent ep->x chains in flight).
__global__ __launch_bounds__(512, 6) void k_conv2(
        const unsigned* __restrict__ Xbf,        // h1 bf16: [NN+1][32] dwords
        const int* __restrict__ off,
        const int* __restrict__ degi,
        const int4* __restrict__ ep,
        const int* __restrict__ perm,
        const unsigned short* __restrict__ Wb2,
        const float* __restrict__ b2,
        float* __restrict__ agg) {
    __shared__ __align__(16) unsigned short hb[26*544];  // 27.6 KB
    unsigned* hb32 = (unsigned*)hb;
    const int t = threadIdx.x, lane = t & 63, w = t >> 6;
    const int n0 = NN - 16 - blockIdx.x * 16;   // LPT order
    const int g = t >> 5;            // node slot 0..15 (one per half-wave)
    const int chp = t & 31;          // channel pair
    const int n = perm[n0 + g];

    f32x2 h[25];
#pragma unroll
    for (int i = 0; i < 25; ++i) h[i] = f32x2{0.f, 0.f};

    const int ebeg = off[n], eend = off[n + 1];
    const float rdeg = 1.f / (float)max(degi[n], 1);

    for (int i = ebeg; i < eend; i += 4) {
        int4 a[4], b[4]; unsigned u[4];
#pragma unroll
        for (int j = 0; j < 4; ++j) {
            a[j] = ld_ep2(ep, (unsigned)(i + j), 0);
            b[j] = ld_ep2(ep, (unsigned)(i + j), 1);
        }
#pragma unroll
        for (int j = 0; j < 4; ++j)
            u[j] = ld_xu(Xbf, (unsigned)a[j].x * 128u + (unsigned)chp * 4u);
        f32x2 dummy = {0.f, 0.f};
#pragma unroll
        for (int j = 0; j < 4; ++j)
            edge_acc2<false>(h, dummy, a[j], b[j], unpack2(u[j]));
    }

    // dword dump address: channels 2chp,2chp+1 are adjacent ushorts
    const int kh = chp >> 4;                 // k-row parity (c>>5)
    const int r0 = (2*chp) & 31;
    const int dw = us_idx(0, r0, g) >> 1;    // dword index within a kk-row
    // ---- part 1: wi 0..12 -> kk = 2*wi + kh (0..25) ----
#pragma unroll
    for (int wi = 0; wi <= 12; ++wi) {
        unsigned pk = (unsigned)f2bf(h[wi].x * rdeg)
                    | ((unsigned)f2bf(h[wi].y * rdeg) << 16);
        hb32[(unsigned)(2*wi + kh)*272u + dw] = pk;
    }
    __syncthreads();

    const int m = lane & 15, qq = lane >> 4;
    f32x4 acc = {0.f, 0.f, 0.f, 0.f};
    if (w < 4) {
        for (int kk = 0; kk < 26; ++kk) {
            bf16x8 av = *(const bf16x8*)&hb[kk*544 + qq*136 + m*8];
            bf16x8 bv = *(const bf16x8*)(Wb2 + (size_t)((kk*4 + w)*64 + lane) * 8);
            acc = __builtin_amdgcn_mfma_f32_16x16x32_bf16(av, bv, acc, 0, 0, 0);
        }
    }
    __syncthreads();

    // ---- part 2: wi 13..24 -> local kk = 2*wi + kh - 26 (0..23); x -> 24+kh
#pragma unroll
    for (int wi = 13; wi < 25; ++wi) {
        unsigned pk = (unsigned)f2bf(h[wi].x * rdeg)
                    | ((unsigned)f2bf(h[wi].y * rdeg) << 16);
        hb32[(unsigned)(2*wi + kh - 26)*272u + dw] = pk;
    }
    hb32[(unsigned)(24 + kh)*272u + dw] = Xbf[(unsigned)n * 32u + (unsigned)chp];
    __syncthreads();

    if (w >= 4) return;
    for (int kk = 0; kk < 26; ++kk) {
        bf16x8 av = *(const bf16x8*)&hb[kk*544 + qq*136 + m*8];
        bf16x8 bv = *(const bf16x8*)(Wb2 + (size_t)(((kk + 26)*4 + w)*64 + lane) * 8);
        acc = __builtin_amdgcn_mfma_f32_16x16x32_bf16(av, bv, acc, 0, 0, 0);
    }
    const int4 pn = ((const int4*)perm)[(n0 >> 2) + qq];
    const int prow[4] = {pn.x, pn.y, pn.z, pn.w};
    const int co = w*16 + m;
    const float bb = b2[co];
#pragma unroll
    for (int rr = 0; rr < 4; ++rr)
        agg[(size_t)prow[rr]*64 + co] = acc[rr] + bb;
}

// ---------------- batch norm ----------------
__global__ __launch_bounds__(256) void k_bnstats(const float* __restrict__ agg, float* stats) {
    __shared__ float sh0[256], sh1[256];
    int t = threadIdx.x;
    float s = 0.f, ss = 0.f;
    int stride = gridDim.x * 256;
    for (int i = blockIdx.x*256 + t; i < NN*64; i += stride) {
        float v = agg[i];
        s += v; ss += v*v;
    }
    sh0[t] = s; sh1[t] = ss;
    __syncthreads();
    if (t < 64) {
        float a = sh0[t] + sh0[t+64] + sh0[t+128] + sh0[t+192];
        float b = sh1[t] + sh1[t+64] + sh1[t+128] + sh1[t+192];
        atomicAdd(&stats[t], a);
        atomicAdd(&stats[64 + t], b);
    }
}

// fused: stats for agg1 (blocks 0..255 -> st2) and aggS (blocks 256..511 -> sts)
__global__ __launch_bounds__(256) void k_bnstats2(const float* __restrict__ a1,
                                                  const float* __restrict__ as,
                                                  float* stats) {
    __shared__ float sh0[256], sh1[256];
    int t = threadIdx.x;
    const float* src = (blockIdx.x < 256) ? a1 : as;
    float* dst = (blockIdx.x < 256) ? (stats + 128) : (stats + 256);
    int bid = (blockIdx.x < 256) ? blockIdx.x : blockIdx.x - 256;
    float s = 0.f, ss = 0.f;
    for (int i = bid*256 + t; i < NN*64; i += 256*256) {
        float v = src[i];
        s += v; ss += v*v;
    }
    sh0[t] = s; sh1[t] = ss;
    __syncthreads();
    if (t < 64) {
        float a = sh0[t] + sh0[t+64] + sh0[t+128] + sh0[t+192];
        float b = sh1[t] + sh1[t+64] + sh1[t+128] + sh1[t+192];
        atomicAdd(&dst[t], a);
        atomicAdd(&dst[64 + t], b);
    }
}

__device__ __forceinline__ float eluf(float u) { return u > 0.f ? u : expm1f(u); }

__global__ __launch_bounds__(256) void k_bn_elu(const float* __restrict__ agg,
                                                const float* __restrict__ stats,
                                                const float* __restrict__ gamma,
                                                const float* __restrict__ beta,
                                                unsigned short* __restrict__ outb) {
    int i = blockIdx.x*256 + threadIdx.x;
    if (i >= NN*16) return;
    float4 v = ((const float4*)agg)[i];
    float r[4] = {v.x, v.y, v.z, v.w};
    int c0 = (i << 2) & 63;
#pragma unroll
    for (int j = 0; j < 4; j++) {
        int c = c0 + j;
        float mu = stats[c] * (1.f/NN);
        float var = stats[64 + c] * (1.f/NN) - mu*mu;
        float sc = gamma[c] * rsqrtf(fmaxf(var, 0.f) + 1e-5f);
        r[j] = eluf((r[j] - mu)*sc + beta[c]);
    }
    uint2 pk;
    pk.x = (unsigned)f2bf(r[0]) | ((unsigned)f2bf(r[1]) << 16);
    pk.y = (unsigned)f2bf(r[2]) | ((unsigned)f2bf(r[3]) << 16);
    ((uint2*)outb)[i] = pk;
}

__global__ __launch_bounds__(256) void k_bn_final(const float* __restrict__ a2,
                                                  const float* __restrict__ st2,
                                                  const float* __restrict__ g2,
                                                  const float* __restrict__ be2,
                                                  const float* __restrict__ as,
                                                  const float* __restrict__ sts,
                                                  const float* __restrict__ gs,
                                                  const float* __restrict__ bes,
                                                  float* __restrict__ out) {
    int i = blockIdx.x*256 + threadIdx.x;
    if (i >= NN*16) return;
    float4 v2 = ((const float4*)a2)[i];
    float4 vs = ((const float4*)as)[i];
    float r2v[4] = {v2.x, v2.y, v2.z, v2.w};
    float rsv[4] = {vs.x, vs.y, vs.z, vs.w};
    float o[4];
    int c0 = (i << 2) & 63;
#pragma unroll
    for (int j = 0; j < 4; j++) {
        int c = c0 + j;
        float mu2 = st2[c] * (1.f/NN);
        float var2 = st2[64 + c] * (1.f/NN) - mu2*mu2;
        float sc2 = g2[c] * rsqrtf(fmaxf(var2, 0.f) + 1e-5f);
        float mus = sts[c] * (1.f/NN);
        float vars = sts[64 + c] * (1.f/NN) - mus*mus;
        float scs = gs[c] * rsqrtf(fmaxf(vars, 0.f) + 1e-5f);
        float u = (r2v[j] - mu2)*sc2 + be2[c] + (rsv[j] - mus)*scs + bes[c];
        o[j] = eluf(u);
    }
    ((float4*)out)[i] = make_float4(o[0], o[1], o[2], o[3]);
}

extern "C" void kernel_launch(void* const* d_in, const int* in_sizes, int n_in,
                              void* d_out, int out_size, void* d_ws, size_t ws_size,
                              hipStream_t stream) {
    const float* x   = (const float*)d_in[0];
    const int*   ei  = (const int*)d_in[1];
    const float* ea  = (const float*)d_in[2];
    const float* w1  = (const float*)d_in[3];
    const float* r1  = (const float*)d_in[4];
    const float* b1  = (const float*)d_in[5];
    const float* g1  = (const float*)d_in[6];
    const float* be1 = (const float*)d_in[7];
    const float* w2  = (const float*)d_in[8];
    const float* r2  = (const float*)d_in[9];
    const float* b2  = (const float*)d_in[10];
    const float* g2  = (const float*)d_in[11];
    const float* be2 = (const float*)d_in[12];
    const float* wsN = (const float*)d_in[13];
    const float* rs  = (const float*)d_in[14];
    const float* bs  = (const float*)d_in[15];
    const float* gs  = (const float*)d_in[16];
    const float* bes = (const float*)d_in[17];
    const int* srcp = ei;
    const int* dstp = ei + NE;

    char* wsb = (char*)d_ws;
    size_t o = 0;
    auto alloc = [&](size_t bytes) -> char* {
        char* p = wsb + o;
        o += (bytes + 255) & ~(size_t)255;
        return p;
    };
    int*    degi    = (int*)   alloc((size_t)NN * 4);
    int*    cur     = (int*)   alloc((size_t)NN * 4);
    int*    off     = (int*)   alloc((size_t)(NN + 1) * 4);
    int*    bsum    = (int*)   alloc(256 * 4);
    int*    bpre    = (int*)   alloc(256 * 4);
    int*    dcnt    = (int*)   alloc(DBINS * 4);
    int*    dcur    = (int*)   alloc(DBINS * 4);
    int*    dbase   = (int*)   alloc(DBINS * 4);
    int*    perm    = (int*)   alloc((size_t)NN * 4);
    int4*   ep      = (int4*)  alloc(((size_t)NE + 3*NN + 64) * 32);  // padded
    unsigned short* Wb1 = (unsigned short*)alloc(26 * 4096);
    unsigned short* WbS = (unsigned short*)alloc(2 * 4096);
    unsigned short* Wb2 = (unsigned short*)alloc(52 * 4096);
    float*  agg1    = (float*) alloc((size_t)NN * 64 * 4);
    float*  aggS    = (float*) alloc((size_t)NN * 64 * 4);
    unsigned short* h1bf = (unsigned short*)alloc((size_t)(NN + 1) * 64 * 2);
    unsigned short* xbf  = (unsigned short*)alloc((size_t)(NN + 1) * 32 * 2);
    float*  stats   = (float*) alloc(384 * 4);
    (void)ws_size; (void)in_sizes; (void)n_in; (void)out_size;

    float* out = (float*)d_out;

    k_zero<<<196, 256, 0, stream>>>(degi, cur, stats, dcnt, dcur,
                                    (unsigned*)(xbf + (size_t)NN * 32),
                                    (unsigned*)(h1bf + (size_t)NN * 64));
    k_hist<<<3125, 256, 0, stream>>>(dstp, degi);
    k_sbdh<<<245, 256, 0, stream>>>(degi, off, bsum, dcnt);
    k_topscan<<<2, 256, 0, stream>>>(bsum, bpre, 49, dcnt, dbase);
    k_scan_add<<<196, 256, 0, stream>>>(off, bpre, degi);
    k_pscatter_pad<<<196, 256, 0, stream>>>(degi, dbase, dcur, perm, off, ep);
    k_scatter_prep<<<4768, 256, 0, stream>>>(srcp, dstp, ea, off, cur, ep,
                                             x, xbf, w1, r1, Wb1,
                                             wsN, rs, WbS, w2, r2, Wb2);

    k_conv1s<<<3125, 512, 0, stream>>>((const unsigned*)xbf, off, degi, ep, perm,
                                       Wb1, WbS, b1, bs, agg1, aggS);
    k_bnstats<<<256, 256, 0, stream>>>(agg1, stats);
    k_bn_elu<<<3125, 256, 0, stream>>>(agg1, stats, g1, be1, h1bf);

    k_conv2<<<3125, 512, 0, stream>>>((const unsigned*)h1bf, off, degi, ep, perm,
                                      Wb2, b2, agg1);
    k_bnstats2<<<512, 256, 0, stream>>>(agg1, aggS, stats);
    k_bn_final<<<3125, 256, 0, stream>>>(agg1, stats + 128, g2, be2,
                                         aggS, stats + 256, gs, bes, out);
}

// Round 16
// 412.768 us; speedup vs baseline: 1.0268x; 1.0268x over previous
//
#include <hip/hip_runtime.h>

#define NN 50000
#define NE 800000
#define DBINS 1024

typedef __attribute__((ext_vector_type(8))) short bf16x8;
typedef __attribute__((ext_vector_type(4))) float f32x4;
typedef __attribute__((ext_vector_type(2))) float f32x2;

__device__ __forceinline__ unsigned short f2bf(float f) {
    union { float f; unsigned u; } v; v.f = f;
    unsigned r = v.u + 0x7FFFu + ((v.u >> 16) & 1u);
    return (unsigned short)(r >> 16);
}

// 32-bit-offset gathers (uniform 64-bit base + 32-bit voffset)
__device__ __forceinline__ int4 ld_ep2(const int4* ep, unsigned idx, int which) {
    return *(const int4*)((const char*)ep + (size_t)(idx * 32u + (unsigned)which * 16u));
}
__device__ __forceinline__ unsigned ld_xu(const unsigned* X, unsigned byteoff) {
    return *(const unsigned*)((const char*)X + (size_t)byteoff);
}

// dword of 2 packed bf16 (lo, hi) -> f32x2 {lo, hi}
__device__ __forceinline__ f32x2 unpack2(unsigned u) {
    union { unsigned u; float f; } a, b;
    a.u = u << 16;
    b.u = u & 0xFFFF0000u;
    return f32x2{a.f, b.f};
}

// ---- forced VOP3P packed-f32 with op_sel broadcasts (validated r3/r4) ----
__device__ __forceinline__ f32x2 pk_mul_hib(f32x2 w, f32x2 x) {
    f32x2 d;
    asm("v_pk_mul_f32 %0, %1, %2 op_sel:[1,0] op_sel_hi:[1,1]"
        : "=v"(d) : "v"(w), "v"(x));
    return d;
}
__device__ __forceinline__ void pk_fma_lob(f32x2& h, f32x2 w, f32x2 t) {
    asm("v_pk_fma_f32 %0, %1, %2, %0 op_sel:[0,0,0] op_sel_hi:[0,1,1]"
        : "+v"(h) : "v"(w), "v"(t));
}

// bf16 LDS A-fragment layout (16 nodes):
//   element (kstep kk, r = k&31, node m) at ushort index
//   kk*544 + (r>>3)*136 + m*8 + (r&7)
__device__ __forceinline__ int us_idx(int kk, int r, int m) {
    return kk*544 + (r >> 3)*136 + m*8 + (r & 7);
}

// packed hat-weight accumulate; weights preloaded per edge (bf16 pairs).
// Branch-free dense form: 25 pk_fma — register-resident. 2-edge working set
// is the verified register-feasible maximum (4-edge batch spills: r15).
template<bool HS>
__device__ __forceinline__ void edge_acc2(f32x2* h, f32x2& hs,
                                          const int4& pa, const int4& pb, f32x2 x) {
    f32x2 wxy[5];
    wxy[0] = unpack2((unsigned)pa.y);
    wxy[1] = unpack2((unsigned)pa.z);
    wxy[2] = unpack2((unsigned)pa.w);
    wxy[3] = unpack2((unsigned)pb.x);
    wxy[4] = unpack2((unsigned)pb.y);
    if (HS) hs += x;
#pragma unroll
    for (int r1 = 0; r1 < 5; ++r1) {
        f32x2 ty = pk_mul_hib(wxy[r1], x);
#pragma unroll
        for (int r0 = 0; r0 < 5; ++r0)
            pk_fma_lob(h[r1*5 + r0], wxy[r0], ty);
    }
}

__device__ __forceinline__ float eh_reduce(f32x2 v, int eh, int stride) {
    float mine  = eh ? v.y : v.x;
    float other = eh ? v.x : v.y;
    return mine + __shfl_xor(other, stride);
}

// ---------------- setup kernels ----------------
__global__ __launch_bounds__(256) void k_zero(int* degi, int* cur, float* stats,
                                              int* dcnt, int* dcur,
                                              unsigned* xz, unsigned* hz) {
    int i = blockIdx.x*256 + threadIdx.x;
    int stride = gridDim.x*256;
    for (int j = i; j < NN; j += stride) { degi[j] = 0; cur[j] = 0; }
    if (i < 384) stats[i] = 0.f;
    if (i < DBINS) { dcnt[i] = 0; dcur[i] = 0; }
    if (i < 16) xz[i] = 0u;
    if (i < 32) hz[i] = 0u;
}

__global__ __launch_bounds__(256) void k_hist(const int* __restrict__ dst, int* degi) {
    int e = blockIdx.x*256 + threadIdx.x;
    if (e < NE) atomicAdd(&degi[dst[e]], 1);
}

// fused: blocks 0..48 = scan of CEIL4(deg) -> padded offsets;
//        blocks 49..244 = 1024-bin LDS-staged degree histogram.
__global__ __launch_bounds__(256) void k_sbdh(const int* __restrict__ degi,
                                              int* off, int* bsum, int* dcnt) {
    __shared__ int lh[DBINS];
    int t = threadIdx.x;
    if (blockIdx.x < 49) {
        int base = blockIdx.x * 1024;
        int v[4]; int s = 0;
#pragma unroll
        for (int j = 0; j < 4; j++) {
            int idx = base + t*4 + j;
            v[j] = (idx < NN) ? ((degi[idx] + 3) & ~3) : 0;
            s += v[j];
        }
        lh[t] = s; __syncthreads();
        for (int ofs = 1; ofs < 256; ofs <<= 1) {
            int x = (t >= ofs) ? lh[t - ofs] : 0;
            __syncthreads();
            lh[t] += x;
            __syncthreads();
        }
        int ex = lh[t] - s;
#pragma unroll
        for (int j = 0; j < 4; j++) {
            int idx = base + t*4 + j;
            if (idx < NN) off[idx] = ex;
            ex += v[j];
        }
        if (t == 255) bsum[blockIdx.x] = lh[255];
    } else {
#pragma unroll
        for (int j = 0; j < DBINS/256; ++j) lh[t + 256*j] = 0;
        __syncthreads();
        int n = (blockIdx.x - 49)*256 + t;
        if (n < NN) atomicAdd(&lh[min(degi[n], DBINS-1)], 1);
        __syncthreads();
#pragma unroll
        for (int j = 0; j < DBINS/256; ++j) {
            int b = t + 256*j;
            if (lh[b]) atomicAdd(&dcnt[b], lh[b]);
        }
    }
}

// fused: block 0 = top-level scan of bsum; block 1 = 1024-bin degree scan
__global__ __launch_bounds__(256) void k_topscan(const int* __restrict__ bsum,
                                                 int* bpre, int nb,
                                                 const int* __restrict__ dcnt,
                                                 int* dbase) {
    __shared__ int sh[256];
    int t = threadIdx.x;
    if (blockIdx.x == 0) {
        int s = (t < nb) ? bsum[t] : 0;
        sh[t] = s; __syncthreads();
        for (int ofs = 1; ofs < 256; ofs <<= 1) {
            int x = (t >= ofs) ? sh[t - ofs] : 0;
            __syncthreads();
            sh[t] += x;
            __syncthreads();
        }
        if (t < nb) bpre[t] = sh[t] - s;
    } else {
        int v[4]; int s = 0;
#pragma unroll
        for (int j = 0; j < 4; j++) { v[j] = dcnt[t*4 + j]; s += v[j]; }
        sh[t] = s; __syncthreads();
        for (int ofs = 1; ofs < 256; ofs <<= 1) {
            int x = (t >= ofs) ? sh[t - ofs] : 0;
            __syncthreads();
            sh[t] += x;
            __syncthreads();
        }
        int ex = sh[t] - s;
#pragma unroll
        for (int j = 0; j < 4; j++) { dbase[t*4 + j] = ex; ex += v[j]; }
    }
}

__global__ __launch_bounds__(256) void k_scan_add(int* off, const int* __restrict__ bpre,
                                                  const int* __restrict__ degi) {
    int i = blockIdx.x*256 + threadIdx.x;
    if (i < NN) {
        int v = off[i] + bpre[i >> 10];
        off[i] = v;
        if (i == NN - 1) off[NN] = v + ((degi[i] + 3) & ~3);
    }
}

// fused: counting-sort scatter (LDS-staged) + pad fill
__global__ __launch_bounds__(256) void k_pscatter_pad(const int* __restrict__ degi,
                                                      const int* __restrict__ dbase,
                                                      int* dcur, int* perm,
                                                      const int* __restrict__ off,
                                                      int4* __restrict__ ep) {
    __shared__ int lh[DBINS];
    __shared__ int lb[DBINS];
    int t = threadIdx.x;
#pragma unroll
    for (int j = 0; j < DBINS/256; ++j) lh[t + 256*j] = 0;
    __syncthreads();
    int n = blockIdx.x*256 + t;
    int d = 0, lr = 0;
    bool act = (n < NN);
    if (act) {
        d = min(degi[n], DBINS-1);
        lr = atomicAdd(&lh[d], 1);
    }
    __syncthreads();
#pragma unroll
    for (int j = 0; j < DBINS/256; ++j) {
        int b = t + 256*j;
        int c = lh[b];
        lb[b] = c ? atomicAdd(&dcur[b], c) : 0;
    }
    __syncthreads();
    if (act) {
        perm[dbase[d] + lb[d] + lr] = n;
        int base = off[n] + degi[n];
        int end  = off[n + 1];
        for (int p = base; p < end; ++p) {
            ep[2*p]     = make_int4(NN, 0, 0, 0);
            ep[2*p + 1] = make_int4(0, 0, 0, 0);
        }
    }
}

__device__ __forceinline__ void wprep_body(int tid, const float* W, const float* root,
                                           int KTC, unsigned short* Wb) {
    int lane = tid & 63, cot = (tid >> 6) & 3, kk = tid >> 8;
    int co = 16*cot + (lane & 15);
    int kbase = kk*32 + ((lane >> 4) * 8);
    union { unsigned short s[8]; uint4 v; } u;
#pragma unroll
    for (int j = 0; j < 8; j++) {
        int k = kbase + j;
        float val = (k < KTC) ? W[(size_t)k*64 + co] : root[(size_t)(k - KTC)*64 + co];
        u.s[j] = f2bf(val);
    }
    *(uint4*)(Wb + (size_t)tid * 8) = u.v;
}

// fused: blocks 0..3124 edge scatter (dense weight records);
//        blocks 3125..4687 x->bf16; 4688..4713 Wb1; 4714..4715 WbS; rest Wb2.
__global__ __launch_bounds__(256) void k_scatter_prep(
        const int* __restrict__ src, const int* __restrict__ dst,
        const float* __restrict__ ea, const int* __restrict__ off, int* cur,
        int4* __restrict__ ep,
        const float* __restrict__ x, unsigned short* __restrict__ xb,
        const float* __restrict__ w1, const float* __restrict__ r1,
        unsigned short* Wb1,
        const float* __restrict__ wsN, const float* __restrict__ rs,
        unsigned short* WbS,
        const float* __restrict__ w2, const float* __restrict__ r2,
        unsigned short* Wb2) {
    int b = blockIdx.x, t = threadIdx.x;
    if (b < 3125) {
        int e = b*256 + t;
        if (e >= NE) return;
        int d = dst[e];
        int p = off[d] + atomicAdd(&cur[d], 1);
        float v0 = ea[2*e]     * 4.f;
        float v1 = ea[2*e + 1] * 4.f;
        unsigned w[5];
#pragma unroll
        for (int r = 0; r < 5; ++r) {
            float wx = fmaxf(1.f - fabsf(v0 - (float)r), 0.f);
            float wy = fmaxf(1.f - fabsf(v1 - (float)r), 0.f);
            w[r] = (unsigned)f2bf(wx) | ((unsigned)f2bf(wy) << 16);
        }
        ep[2*p]     = make_int4(src[e], (int)w[0], (int)w[1], (int)w[2]);
        ep[2*p + 1] = make_int4((int)w[3], (int)w[4], 0, 0);
    } else if (b < 3125 + 1563) {
        int i = (b - 3125)*256 + t;
        if (i >= NN*8) return;
        float4 v = ((const float4*)x)[i];
        uint2 pk;
        pk.x = (unsigned)f2bf(v.x) | ((unsigned)f2bf(v.y) << 16);
        pk.y = (unsigned)f2bf(v.z) | ((unsigned)f2bf(v.w) << 16);
        ((uint2*)xb)[i] = pk;
    } else if (b < 3125 + 1589) {
        wprep_body((b - 3125 - 1563)*256 + t, w1, r1, 800, Wb1);
    } else if (b < 3125 + 1591) {
        wprep_body((b - 3125 - 1589)*256 + t, wsN, rs, 32, WbS);
    } else {
        wprep_body((b - 3125 - 1591)*256 + t, w2, r2, 1600, Wb2);
    }
}

// ---------------- conv1 + convS fused: 16 nodes/block ----------------
// LPT order: heaviest (highest-degree) blocks first (perm is degree-ascending).
__global__ __launch_bounds__(512, 4) void k_conv1s(
        const unsigned* __restrict__ Xbf,        // [NN+1][16] dwords (32 bf16 ch)
        const int* __restrict__ off,
        const int* __restrict__ degi,
        const int4* __restrict__ ep,
        const int* __restrict__ perm,
        const unsigned short* __restrict__ Wb1,
        const unsigned short* __restrict__ WbS,
        const float* __restrict__ b1,
        const float* __restrict__ bs,
        float* __restrict__ agg1,
        float* __restrict__ aggS) {
    __shared__ __align__(16) unsigned short hb[28*544];  // 30.5 KB
    const int t = threadIdx.x;
    const int g = t >> 5;
    const int q = t & 31;
    const int chp = q & 15;
    const int eh = q >> 4;
    const int n0 = NN - 16 - blockIdx.x * 16;   // LPT order
    const int n = perm[n0 + g];

    f32x2 h[25], hs = {0.f, 0.f};
#pragma unroll
    for (int i = 0; i < 25; ++i) h[i] = f32x2{0.f, 0.f};

    const int ebeg = off[n], eend = off[n + 1];
    const float rdeg = 1.f / (float)max(degi[n], 1);

    for (int i = ebeg; i < eend; i += 4) {
        const unsigned i0 = (unsigned)(i + eh), i1 = (unsigned)(i + 2 + eh);
        int4 a0 = ld_ep2(ep, i0, 0), b0 = ld_ep2(ep, i0, 1);
        int4 a1 = ld_ep2(ep, i1, 0), b1 = ld_ep2(ep, i1, 1);
        unsigned u0 = ld_xu(Xbf, (unsigned)a0.x * 64u + (unsigned)chp * 4u);
        unsigned u1 = ld_xu(Xbf, (unsigned)a1.x * 64u + (unsigned)chp * 4u);
        edge_acc2<true>(h, hs, a0, b0, unpack2(u0));
        edge_acc2<true>(h, hs, a1, b1, unpack2(u1));
    }

    const int c = 2*chp + eh;
    const int bw = us_idx(0, c, g);
#pragma unroll
    for (int wi = 0; wi < 25; ++wi)
        hb[wi*544 + bw] = f2bf(eh_reduce(h[wi], eh, 16) * rdeg);
    hb[26*544 + bw] = f2bf(eh_reduce(hs, eh, 16) * rdeg);
    {
        unsigned ux = Xbf[(unsigned)n * 16u + (unsigned)chp];
        unsigned short xb = eh ? (unsigned short)(ux >> 16)
                               : (unsigned short)(ux & 0xFFFFu);
        hb[25*544 + bw] = xb;
        hb[27*544 + bw] = xb;
    }
    __syncthreads();

    const int lane = t & 63, w = t >> 6;
    const int m = lane & 15, qq = lane >> 4;
    const int co = (w & 3)*16 + m;
    const int4 pn = ((const int4*)perm)[(n0 >> 2) + qq];
    const int prow[4] = {pn.x, pn.y, pn.z, pn.w};
    if (w < 4) {
        f32x4 acc = {0.f, 0.f, 0.f, 0.f};
        for (int kk = 0; kk < 26; ++kk) {
            bf16x8 av = *(const bf16x8*)&hb[kk*544 + qq*136 + m*8];
            bf16x8 bv = *(const bf16x8*)(Wb1 + (size_t)((kk*4 + w)*64 + lane) * 8);
            acc = __builtin_amdgcn_mfma_f32_16x16x32_bf16(av, bv, acc, 0, 0, 0);
        }
        const float bb = b1[co];
#pragma unroll
        for (int r = 0; r < 4; ++r)
            agg1[(size_t)prow[r]*64 + co] = acc[r] + bb;
    } else {
        f32x4 accs = {0.f, 0.f, 0.f, 0.f};
#pragma unroll
        for (int s = 0; s < 2; ++s) {
            bf16x8 av = *(const bf16x8*)&hb[(26 + s)*544 + qq*136 + m*8];
            bf16x8 bv = *(const bf16x8*)(WbS + (size_t)((s*4 + (w & 3))*64 + lane) * 8);
            accs = __builtin_amdgcn_mfma_f32_16x16x32_bf16(av, bv, accs, 0, 0, 0);
        }
        const float bb = bs[co];
#pragma unroll
        for (int r = 0; r < 4; ++r)
            aggS[(size_t)prow[r]*64 + co] = accs[r] + bb;
    }
}

// ---------------- conv2: 16 nodes/block, K-split phase B ----------------
// 512 threads, 8 waves. Half-wave (t>>5) owns one node; lane chp = channel
// pair (c0=2chp, c1=2chp+1) -> no eh_reduce, dword dumps (conflict-free).
// LDS holds 26 of 52 K-steps (27.6 KB): dump wi 0..12 -> MFMA -> barrier ->
// dump wi 13..24 + x -> MFMA. LPT block order. 2-edge loop (register floor).
__global__ __launch_bounds__(512, 6) void k_conv2(
        const unsigned* __restrict__ Xbf,        // h1 bf16: [NN+1][32] dwords
        const int* __restrict__ off,
        const int* __restrict__ degi,
        const int4* __restrict__ ep,
        const int* __restrict__ perm,
        const unsigned short* __restrict__ Wb2,
        const float* __restrict__ b2,
        float* __restrict__ agg) {
    __shared__ __align__(16) unsigned short hb[26*544];  // 27.6 KB
    unsigned* hb32 = (unsigned*)hb;
    const int t = threadIdx.x, lane = t & 63, w = t >> 6;
    const int n0 = NN - 16 - blockIdx.x * 16;   // LPT order
    const int g = t >> 5;            // node slot 0..15 (one per half-wave)
    const int chp = t & 31;          // channel pair
    const int n = perm[n0 + g];

    f32x2 h[25];
#pragma unroll
    for (int i = 0; i < 25; ++i) h[i] = f32x2{0.f, 0.f};

    const int ebeg = off[n], eend = off[n + 1];
    const float rdeg = 1.f / (float)max(degi[n], 1);

    for (int i = ebeg; i < eend; i += 2) {
        int4 a0 = ld_ep2(ep, (unsigned)i, 0),       b0 = ld_ep2(ep, (unsigned)i, 1);
        int4 a1 = ld_ep2(ep, (unsigned)(i+1), 0),   b1 = ld_ep2(ep, (unsigned)(i+1), 1);
        unsigned u0 = ld_xu(Xbf, (unsigned)a0.x * 128u + (unsigned)chp * 4u);
        unsigned u1 = ld_xu(Xbf, (unsigned)a1.x * 128u + (unsigned)chp * 4u);
        f32x2 dummy = {0.f, 0.f};
        edge_acc2<false>(h, dummy, a0, b0, unpack2(u0));
        edge_acc2<false>(h, dummy, a1, b1, unpack2(u1));
    }

    // dword dump address: channels 2chp,2chp+1 are adjacent ushorts
    const int kh = chp >> 4;                 // k-row parity (c>>5)
    const int r0 = (2*chp) & 31;
    const int dw = us_idx(0, r0, g) >> 1;    // dword index within a kk-row
    // ---- part 1: wi 0..12 -> kk = 2*wi + kh (0..25) ----
#pragma unroll
    for (int wi = 0; wi <= 12; ++wi) {
        unsigned pk = (unsigned)f2bf(h[wi].x * rdeg)
                    | ((unsigned)f2bf(h[wi].y * rdeg) << 16);
        hb32[(unsigned)(2*wi + kh)*272u + dw] = pk;
    }
    __syncthreads();

    const int m = lane & 15, qq = lane >> 4;
    f32x4 acc = {0.f, 0.f, 0.f, 0.f};
    if (w < 4) {
        for (int kk = 0; kk < 26; ++kk) {
            bf16x8 av = *(const bf16x8*)&hb[kk*544 + qq*136 + m*8];
            bf16x8 bv = *(const bf16x8*)(Wb2 + (size_t)((kk*4 + w)*64 + lane) * 8);
            acc = __builtin_amdgcn_mfma_f32_16x16x32_bf16(av, bv, acc, 0, 0, 0);
        }
    }
    __syncthreads();

    // ---- part 2: wi 13..24 -> local kk = 2*wi + kh - 26 (0..23); x -> 24+kh
#pragma unroll
    for (int wi = 13; wi < 25; ++wi) {
        unsigned pk = (unsigned)f2bf(h[wi].x * rdeg)
                    | ((unsigned)f2bf(h[wi].y * rdeg) << 16);
        hb32[(unsigned)(2*wi + kh - 26)*272u + dw] = pk;
    }
    hb32[(unsigned)(24 + kh)*272u + dw] = Xbf[(unsigned)n * 32u + (unsigned)chp];
    __syncthreads();

    if (w >= 4) return;
    for (int kk = 0; kk < 26; ++kk) {
        bf16x8 av = *(const bf16x8*)&hb[kk*544 + qq*136 + m*8];
        bf16x8 bv = *(const bf16x8*)(Wb2 + (size_t)(((kk + 26)*4 + w)*64 + lane) * 8);
        acc = __builtin_amdgcn_mfma_f32_16x16x32_bf16(av, bv, acc, 0, 0, 0);
    }
    const int4 pn = ((const int4*)perm)[(n0 >> 2) + qq];
    const int prow[4] = {pn.x, pn.y, pn.z, pn.w};
    const int co = w*16 + m;
    const float bb = b2[co];
#pragma unroll
    for (int rr = 0; rr < 4; ++rr)
        agg[(size_t)prow[rr]*64 + co] = acc[rr] + bb;
}

// ---------------- batch norm ----------------
__global__ __launch_bounds__(256) void k_bnstats(const float* __restrict__ agg, float* stats) {
    __shared__ float sh0[256], sh1[256];
    int t = threadIdx.x;
    float s = 0.f, ss = 0.f;
    int stride = gridDim.x * 256;
    for (int i = blockIdx.x*256 + t; i < NN*64; i += stride) {
        float v = agg[i];
        s += v; ss += v*v;
    }
    sh0[t] = s; sh1[t] = ss;
    __syncthreads();
    if (t < 64) {
        float a = sh0[t] + sh0[t+64] + sh0[t+128] + sh0[t+192];
        float b = sh1[t] + sh1[t+64] + sh1[t+128] + sh1[t+192];
        atomicAdd(&stats[t], a);
        atomicAdd(&stats[64 + t], b);
    }
}

// fused: stats for agg1 (blocks 0..255 -> st2) and aggS (blocks 256..511 -> sts)
__global__ __launch_bounds__(256) void k_bnstats2(const float* __restrict__ a1,
                                                  const float* __restrict__ as,
                                                  float* stats) {
    __shared__ float sh0[256], sh1[256];
    int t = threadIdx.x;
    const float* src = (blockIdx.x < 256) ? a1 : as;
    float* dst = (blockIdx.x < 256) ? (stats + 128) : (stats + 256);
    int bid = (blockIdx.x < 256) ? blockIdx.x : blockIdx.x - 256;
    float s = 0.f, ss = 0.f;
    for (int i = bid*256 + t; i < NN*64; i += 256*256) {
        float v = src[i];
        s += v; ss += v*v;
    }
    sh0[t] = s; sh1[t] = ss;
    __syncthreads();
    if (t < 64) {
        float a = sh0[t] + sh0[t+64] + sh0[t+128] + sh0[t+192];
        float b = sh1[t] + sh1[t+64] + sh1[t+128] + sh1[t+192];
        atomicAdd(&dst[t], a);
        atomicAdd(&dst[64 + t], b);
    }
}

__device__ __forceinline__ float eluf(float u) { return u > 0.f ? u : expm1f(u); }

__global__ __launch_bounds__(256) void k_bn_elu(const float* __restrict__ agg,
                                                const float* __restrict__ stats,
                                                const float* __restrict__ gamma,
                                                const float* __restrict__ beta,
                                                unsigned short* __restrict__ outb) {
    int i = blockIdx.x*256 + threadIdx.x;
    if (i >= NN*16) return;
    float4 v = ((const float4*)agg)[i];
    float r[4] = {v.x, v.y, v.z, v.w};
    int c0 = (i << 2) & 63;
#pragma unroll
    for (int j = 0; j < 4; j++) {
        int c = c0 + j;
        float mu = stats[c] * (1.f/NN);
        float var = stats[64 + c] * (1.f/NN) - mu*mu;
        float sc = gamma[c] * rsqrtf(fmaxf(var, 0.f) + 1e-5f);
        r[j] = eluf((r[j] - mu)*sc + beta[c]);
    }
    uint2 pk;
    pk.x = (unsigned)f2bf(r[0]) | ((unsigned)f2bf(r[1]) << 16);
    pk.y = (unsigned)f2bf(r[2]) | ((unsigned)f2bf(r[3]) << 16);
    ((uint2*)outb)[i] = pk;
}

__global__ __launch_bounds__(256) void k_bn_final(const float* __restrict__ a2,
                                                  const float* __restrict__ st2,
                                                  const float* __restrict__ g2,
                                                  const float* __restrict__ be2,
                                                  const float* __restrict__ as,
                                                  const float* __restrict__ sts,
                                                  const float* __restrict__ gs,
                                                  const float* __restrict__ bes,
                                                  float* __restrict__ out) {
    int i = blockIdx.x*256 + threadIdx.x;
    if (i >= NN*16) return;
    float4 v2 = ((const float4*)a2)[i];
    float4 vs = ((const float4*)as)[i];
    float r2v[4] = {v2.x, v2.y, v2.z, v2.w};
    float rsv[4] = {vs.x, vs.y, vs.z, vs.w};
    float o[4];
    int c0 = (i << 2) & 63;
#pragma unroll
    for (int j = 0; j < 4; j++) {
        int c = c0 + j;
        float mu2 = st2[c] * (1.f/NN);
        float var2 = st2[64 + c] * (1.f/NN) - mu2*mu2;
        float sc2 = g2[c] * rsqrtf(fmaxf(var2, 0.f) + 1e-5f);
        float mus = sts[c] * (1.f/NN);
        float vars = sts[64 + c] * (1.f/NN) - mus*mus;
        float scs = gs[c] * rsqrtf(fmaxf(vars, 0.f) + 1e-5f);
        float u = (r2v[j] - mu2)*sc2 + be2[c] + (rsv[j] - mus)*scs + bes[c];
        o[j] = eluf(u);
    }
    ((float4*)out)[i] = make_float4(o[0], o[1], o[2], o[3]);
}

extern "C" void kernel_launch(void* const* d_in, const int* in_sizes, int n_in,
                              void* d_out, int out_size, void* d_ws, size_t ws_size,
                              hipStream_t stream) {
    const float* x   = (const float*)d_in[0];
    const int*   ei  = (const int*)d_in[1];
    const float* ea  = (const float*)d_in[2];
    const float* w1  = (const float*)d_in[3];
    const float* r1  = (const float*)d_in[4];
    const float* b1  = (const float*)d_in[5];
    const float* g1  = (const float*)d_in[6];
    const float* be1 = (const float*)d_in[7];
    const float* w2  = (const float*)d_in[8];
    const float* r2  = (const float*)d_in[9];
    const float* b2  = (const float*)d_in[10];
    const float* g2  = (const float*)d_in[11];
    const float* be2 = (const float*)d_in[12];
    const float* wsN = (const float*)d_in[13];
    const float* rs  = (const float*)d_in[14];
    const float* bs  = (const float*)d_in[15];
    const float* gs  = (const float*)d_in[16];
    const float* bes = (const float*)d_in[17];
    const int* srcp = ei;
    const int* dstp = ei + NE;

    char* wsb = (char*)d_ws;
    size_t o = 0;
    auto alloc = [&](size_t bytes) -> char* {
        char* p = wsb + o;
        o += (bytes + 255) & ~(size_t)255;
        return p;
    };
    int*    degi    = (int*)   alloc((size_t)NN * 4);
    int*    cur     = (int*)   alloc((size_t)NN * 4);
    int*    off     = (int*)   alloc((size_t)(NN + 1) * 4);
    int*    bsum    = (int*)   alloc(256 * 4);
    int*    bpre    = (int*)   alloc(256 * 4);
    int*    dcnt    = (int*)   alloc(DBINS * 4);
    int*    dcur    = (int*)   alloc(DBINS * 4);
    int*    dbase   = (int*)   alloc(DBINS * 4);
    int*    perm    = (int*)   alloc((size_t)NN * 4);
    int4*   ep      = (int4*)  alloc(((size_t)NE + 3*NN + 64) * 32);  // padded
    unsigned short* Wb1 = (unsigned short*)alloc(26 * 4096);
    unsigned short* WbS = (unsigned short*)alloc(2 * 4096);
    unsigned short* Wb2 = (unsigned short*)alloc(52 * 4096);
    float*  agg1    = (float*) alloc((size_t)NN * 64 * 4);
    float*  aggS    = (float*) alloc((size_t)NN * 64 * 4);
    unsigned short* h1bf = (unsigned short*)alloc((size_t)(NN + 1) * 64 * 2);
    unsigned short* xbf  = (unsigned short*)alloc((size_t)(NN + 1) * 32 * 2);
    float*  stats   = (float*) alloc(384 * 4);
    (void)ws_size; (void)in_sizes; (void)n_in; (void)out_size;

    float* out = (float*)d_out;

    k_zero<<<196, 256, 0, stream>>>(degi, cur, stats, dcnt, dcur,
                                    (unsigned*)(xbf + (size_t)NN * 32),
                                    (unsigned*)(h1bf + (size_t)NN * 64));
    k_hist<<<3125, 256, 0, stream>>>(dstp, degi);
    k_sbdh<<<245, 256, 0, stream>>>(degi, off, bsum, dcnt);
    k_topscan<<<2, 256, 0, stream>>>(bsum, bpre, 49, dcnt, dbase);
    k_scan_add<<<196, 256, 0, stream>>>(off, bpre, degi);
    k_pscatter_pad<<<196, 256, 0, stream>>>(degi, dbase, dcur, perm, off, ep);
    k_scatter_prep<<<4768, 256, 0, stream>>>(srcp, dstp, ea, off, cur, ep,
                                             x, xbf, w1, r1, Wb1,
                                             wsN, rs, WbS, w2, r2, Wb2);

    k_conv1s<<<3125, 512, 0, stream>>>((const unsigned*)xbf, off, degi, ep, perm,
                                       Wb1, WbS, b1, bs, agg1, aggS);
    k_bnstats<<<256, 256, 0, stream>>>(agg1, stats);
    k_bn_elu<<<3125, 256, 0, stream>>>(agg1, stats, g1, be1, h1bf);

    k_conv2<<<3125, 512, 0, stream>>>((const unsigned*)h1bf, off, degi, ep, perm,
                                      Wb2, b2, agg1);
    k_bnstats2<<<512, 256, 0, stream>>>(agg1, aggS, stats);
    k_bn_final<<<3125, 256, 0, stream>>>(agg1, stats + 128, g2, be2,
                                         aggS, stats + 256, gs, bes, out);
}